// Round 1
// baseline (28400.903 us; speedup 1.0000x reference)
//
#include <hip/hip_runtime.h>
#include <math.h>

#define T_SEQ 4096
#define NWG 8   // total workgroups in each lstm_rec launch (4 per direction)

__device__ __forceinline__ float sigmoidf_(float x) {
  return 1.0f / (1.0f + expf(-x));
}

// Generation-counter grid barrier across NWG workgroups (device scope).
__device__ __forceinline__ void grid_barrier(int* cnt, int* gen) {
  __syncthreads();
  if (threadIdx.x == 0) {
    int g = __hip_atomic_load(gen, __ATOMIC_RELAXED, __HIP_MEMORY_SCOPE_AGENT);
    int a = __hip_atomic_fetch_add(cnt, 1, __ATOMIC_ACQ_REL, __HIP_MEMORY_SCOPE_AGENT);
    if (a == NWG - 1) {
      __hip_atomic_store(cnt, 0, __ATOMIC_RELAXED, __HIP_MEMORY_SCOPE_AGENT);
      __hip_atomic_store(gen, g + 1, __ATOMIC_RELEASE, __HIP_MEMORY_SCOPE_AGENT);
    } else {
      while (__hip_atomic_load(gen, __ATOMIC_ACQUIRE, __HIP_MEMORY_SCOPE_AGENT) == g) { }
    }
  }
  __syncthreads();
}

// X[t][k] = emb[tokens[t]][k], as float4
__global__ void gather_emb(const int* __restrict__ tokens,
                           const float4* __restrict__ emb4,
                           float4* __restrict__ X4) {
  int i = blockIdx.x * 256 + threadIdx.x;   // i < 4096*128
  int t = i >> 7;
  int q = i & 127;
  X4[i] = emb4[(long)tokens[t] * 128 + q];
}

// P[t][j] = bias_ih[j] + bias_hh[j] + sum_k X[src(t)][k] * W[j][k]
// M=4096 rows, N=1024 cols. blockIdx.z selects direction (0=f,1=b).
// For dir b with rev=1, src(t) = 4095 - t (time reversal folded in).
__global__ __launch_bounds__(256) void gemm_proj(
    const float* __restrict__ Xf, const float* __restrict__ Xb, int revb,
    const float* __restrict__ Wf, const float* __restrict__ Wb,
    const float* __restrict__ bihf, const float* __restrict__ bhhf,
    const float* __restrict__ bihb, const float* __restrict__ bhhb,
    float* __restrict__ Pf, float* __restrict__ Pb, int K)
{
  const int dirb = blockIdx.z;
  const float* X  = dirb ? Xb : Xf;
  const float* W  = dirb ? Wb : Wf;
  const float* bih = dirb ? bihb : bihf;
  const float* bhh = dirb ? bhhb : bhhf;
  float* Pp = dirb ? Pb : Pf;
  const int rev = dirb ? revb : 0;

  const int bn = blockIdx.x;   // N tile (16)
  const int bm = blockIdx.y;   // M tile (64)
  const int tid = threadIdx.x;
  const int tx = tid & 15, ty = tid >> 4;

  __shared__ float Xs[16][68];   // [k][row], padded
  __shared__ float Ws[16][68];   // [k][col], padded

  float acc[4][4] = {{0.f}};

  const int lrow = tid >> 2;        // 0..63
  const int lk4  = (tid & 3) * 4;   // 0,4,8,12
  const int xrow = bm * 64 + lrow;
  const int xsrc = rev ? (4095 - xrow) : xrow;
  const float* xptr = X + (long)xsrc * K + lk4;
  const float* wptr = W + (long)(bn * 64 + lrow) * K + lk4;

  for (int k0 = 0; k0 < K; k0 += 16) {
    float4 xv = *(const float4*)(xptr + k0);
    float4 wv = *(const float4*)(wptr + k0);
    __syncthreads();   // protect previous iteration's LDS reads
    Xs[lk4 + 0][lrow] = xv.x; Xs[lk4 + 1][lrow] = xv.y;
    Xs[lk4 + 2][lrow] = xv.z; Xs[lk4 + 3][lrow] = xv.w;
    Ws[lk4 + 0][lrow] = wv.x; Ws[lk4 + 1][lrow] = wv.y;
    Ws[lk4 + 2][lrow] = wv.z; Ws[lk4 + 3][lrow] = wv.w;
    __syncthreads();
    #pragma unroll
    for (int kk = 0; kk < 16; ++kk) {
      float4 a = *(const float4*)(&Xs[kk][ty * 4]);
      float4 b = *(const float4*)(&Ws[kk][tx * 4]);
      acc[0][0] = fmaf(a.x, b.x, acc[0][0]); acc[0][1] = fmaf(a.x, b.y, acc[0][1]);
      acc[0][2] = fmaf(a.x, b.z, acc[0][2]); acc[0][3] = fmaf(a.x, b.w, acc[0][3]);
      acc[1][0] = fmaf(a.y, b.x, acc[1][0]); acc[1][1] = fmaf(a.y, b.y, acc[1][1]);
      acc[1][2] = fmaf(a.y, b.z, acc[1][2]); acc[1][3] = fmaf(a.y, b.w, acc[1][3]);
      acc[2][0] = fmaf(a.z, b.x, acc[2][0]); acc[2][1] = fmaf(a.z, b.y, acc[2][1]);
      acc[2][2] = fmaf(a.z, b.z, acc[2][2]); acc[2][3] = fmaf(a.z, b.w, acc[2][3]);
      acc[3][0] = fmaf(a.w, b.x, acc[3][0]); acc[3][1] = fmaf(a.w, b.y, acc[3][1]);
      acc[3][2] = fmaf(a.w, b.z, acc[3][2]); acc[3][3] = fmaf(a.w, b.w, acc[3][3]);
    }
  }

  const int c0 = bn * 64 + tx * 4;
  #pragma unroll
  for (int i = 0; i < 4; ++i) {
    const int r = bm * 64 + ty * 4 + i;
    float4 o4;
    o4.x = acc[i][0] + bih[c0 + 0] + bhh[c0 + 0];
    o4.y = acc[i][1] + bih[c0 + 1] + bhh[c0 + 1];
    o4.z = acc[i][2] + bih[c0 + 2] + bhh[c0 + 2];
    o4.w = acc[i][3] + bih[c0 + 3] + bhh[c0 + 3];
    *(float4*)(&Pp[(long)r * 1024 + c0]) = o4;
  }
}

// Persistent-weight LSTM recurrence. Grid: (4 WGs, 2 dirs), 512 thr/WG.
// WG w of dir d owns cell indices k in [w*64, w*64+64) and the 4 gate rows
// j = gate*256 + k for those k. Thread t: kb = t>>6 (k-slice of 32),
// jg = t&63 -> 4 outputs m = jg*4..jg*4+3 (m in [0,256), gate = m>>6).
// Weights Whh[j][kb*32..+32] live in 128 VGPRs per thread.
__global__ __launch_bounds__(512, 2) void lstm_rec(
    const float* __restrict__ Pf, const float* __restrict__ Pb,
    const float* __restrict__ Wf, const float* __restrict__ Wb,
    float* __restrict__ houtf, int strf,
    float* __restrict__ houtb, int strb,
    float* __restrict__ out, int layer,
    float* __restrict__ hbuf, int* __restrict__ bar_cnt, int* __restrict__ bar_gen)
{
  const int w = blockIdx.x;     // 0..3
  const int d = blockIdx.y;     // 0..1
  const int t = threadIdx.x;    // 0..511
  const float* __restrict__ P = d ? Pb : Pf;
  const float* __restrict__ W = d ? Wb : Wf;
  float* hout = d ? houtb : houtf;
  const int hstr = d ? strb : strf;
  float* myh = hbuf + d * 512;  // 2 slots x 256 per dir

  const int kb = t >> 6;
  const int jg = t & 63;

  float wreg[128];
  #pragma unroll
  for (int jj = 0; jj < 4; ++jj) {
    const int m = jg * 4 + jj;
    const int j = (m >> 6) * 256 + w * 64 + (m & 63);
    const float4* wrow = (const float4*)(W + j * 256 + kb * 32);
    #pragma unroll
    for (int kq = 0; kq < 8; ++kq) {
      float4 v = wrow[kq];
      wreg[jj * 32 + kq * 4 + 0] = v.x;
      wreg[jj * 32 + kq * 4 + 1] = v.y;
      wreg[jj * 32 + kq * 4 + 2] = v.z;
      wreg[jj * 32 + kq * 4 + 3] = v.w;
    }
  }

  __shared__ float lds_h[256];
  __shared__ float lds_c[64];
  __shared__ float part[8 * 264];   // [kb][m], pad 264 for conflict-free access
  __shared__ float gbuf[256];
  if (t < 256) lds_h[t] = 0.0f;
  if (t < 64)  lds_c[t] = 0.0f;
  __syncthreads();

  const int jred = (t >> 6) * 256 + w * 64 + (t & 63);  // valid for t<256

  for (int step = 0; step < T_SEQ; ++step) {
    float pval = 0.0f;
    if (t < 256) pval = P[step * 1024 + jred];   // prefetch early

    float a0 = 0.f, a1 = 0.f, a2 = 0.f, a3 = 0.f;
    #pragma unroll
    for (int kk = 0; kk < 32; ++kk) {
      const float hk = lds_h[kb * 32 + kk];      // wave-uniform -> broadcast
      a0 = fmaf(wreg[kk],       hk, a0);
      a1 = fmaf(wreg[32 + kk],  hk, a1);
      a2 = fmaf(wreg[64 + kk],  hk, a2);
      a3 = fmaf(wreg[96 + kk],  hk, a3);
    }
    float4 av; av.x = a0; av.y = a1; av.z = a2; av.w = a3;
    *(float4*)(&part[kb * 264 + jg * 4]) = av;
    __syncthreads();

    if (t < 256) {
      float g = pval;
      #pragma unroll
      for (int q = 0; q < 8; ++q) g += part[q * 264 + t];
      gbuf[t] = g;
    }
    __syncthreads();

    if (t < 64) {
      const float gi = gbuf[t];
      const float gf = gbuf[64 + t];
      const float gg = gbuf[128 + t];
      const float go = gbuf[192 + t];
      float c = sigmoidf_(gf) * lds_c[t] + sigmoidf_(gi) * tanhf(gg);
      float h = sigmoidf_(go) * tanhf(c);
      lds_c[t] = c;
      const int slot = step & 1;
      __hip_atomic_store(&myh[slot * 256 + w * 64 + t], h,
                         __ATOMIC_RELAXED, __HIP_MEMORY_SCOPE_AGENT);
      hout[(long)step * hstr + w * 64 + t] = h;
      if (step == T_SEQ - 1) {
        out[layer * 512 + d * 256 + w * 64 + t] = c;          // cell_memories
        out[1024 + layer * 512 + d * 256 + w * 64 + t] = h;   // hidden_states
      }
    }

    grid_barrier(bar_cnt, bar_gen);

    if (t < 256) {
      lds_h[t] = __hip_atomic_load(&myh[(step & 1) * 256 + t],
                                   __ATOMIC_RELAXED, __HIP_MEMORY_SCOPE_AGENT);
    }
    __syncthreads();
  }
}

extern "C" void kernel_launch(void* const* d_in, const int* in_sizes, int n_in,
                              void* d_out, int out_size, void* d_ws, size_t ws_size,
                              hipStream_t stream) {
  const int*   tokens = (const int*)d_in[0];
  const float* emb    = (const float*)d_in[1];
  const float* fWih0 = (const float*)d_in[2];
  const float* fWhh0 = (const float*)d_in[3];
  const float* fbih0 = (const float*)d_in[4];
  const float* fbhh0 = (const float*)d_in[5];
  const float* fWih1 = (const float*)d_in[6];
  const float* fWhh1 = (const float*)d_in[7];
  const float* fbih1 = (const float*)d_in[8];
  const float* fbhh1 = (const float*)d_in[9];
  const float* bWih0 = (const float*)d_in[10];
  const float* bWhh0 = (const float*)d_in[11];
  const float* bbih0 = (const float*)d_in[12];
  const float* bbhh0 = (const float*)d_in[13];
  const float* bWih1 = (const float*)d_in[14];
  const float* bWhh1 = (const float*)d_in[15];
  const float* bbih1 = (const float*)d_in[16];
  const float* bbhh1 = (const float*)d_in[17];

  float* out = (float*)d_out;
  float* ws  = (float*)d_ws;

  // Workspace layout (float offsets):
  //   [0, 2097152)        X (4096x512); reused as H0f/H0b after gemm0
  //   H0f = ws+0 (1048576), H0b = ws+1048576 (1048576)
  //   [2097152, 6291456)  Pf (4096x1024)
  //   [6291456,10485760)  Pb (4096x1024)
  //   [10485760,10486784) hbuf: 2 dirs x 2 slots x 256
  //   [10486784,...)      barrier cnt/gen (ints)
  float* X    = ws;
  float* H0f  = ws;
  float* H0b  = ws + 1048576;
  float* Pf   = ws + 2097152;
  float* Pb   = ws + 6291456;
  float* hbuf = ws + 10485760;
  int*   bar  = (int*)(ws + 10486784);

  hipMemsetAsync(bar, 0, 2 * sizeof(int), stream);

  gather_emb<<<2048, 256, 0, stream>>>(tokens, (const float4*)emb, (float4*)X);

  // Layer 0 input projections (K=512); b-direction reads X time-reversed.
  gemm_proj<<<dim3(16, 64, 2), 256, 0, stream>>>(
      X, X, 1, fWih0, bWih0, fbih0, fbhh0, bbih0, bbhh0, Pf, Pb, 512);

  // Layer 0 recurrence: hidden sequences into H0f/H0b (step order), finals to out.
  lstm_rec<<<dim3(4, 2), 512, 0, stream>>>(
      Pf, Pb, fWhh0, bWhh0, H0f, 256, H0b, 256, out, 0, hbuf, bar, bar + 1);

  // Layer 1 input projections (K=256) on layer-0 hidden sequences (no reversal).
  gemm_proj<<<dim3(16, 64, 2), 256, 0, stream>>>(
      H0f, H0b, 0, fWih1, bWih1, fbih1, fbhh1, bbih1, bbhh1, Pf, Pb, 256);

  // Layer 1 recurrence: f -> out rows forward, b -> out rows reversed (+256 col).
  lstm_rec<<<dim3(4, 2), 512, 0, stream>>>(
      Pf, Pb, fWhh1, bWhh1,
      out + 2048, 512,
      out + 2048 + (long)4095 * 512 + 256, -512,
      out, 1, hbuf, bar, bar + 1);
}

// Round 2
// 14164.758 us; speedup vs baseline: 2.0050x; 2.0050x over previous
//
#include <hip/hip_runtime.h>
#include <math.h>

#define T_SEQ 4096

__device__ __forceinline__ float sigmoidf_(float x) {
  return 1.0f / (1.0f + expf(-x));
}

// X[t][k] = emb[tokens[t]][k], as float4
__global__ void gather_emb(const int* __restrict__ tokens,
                           const float4* __restrict__ emb4,
                           float4* __restrict__ X4) {
  int i = blockIdx.x * 256 + threadIdx.x;   // i < 4096*128
  int t = i >> 7;
  int q = i & 127;
  X4[i] = emb4[(long)tokens[t] * 128 + q];
}

// P[t][j] = bias_ih[j] + bias_hh[j] + sum_k X[src(t)][k] * W[j][k]
// M=4096 rows, N=1024 cols. blockIdx.z selects direction (0=f,1=b).
__global__ __launch_bounds__(256) void gemm_proj(
    const float* __restrict__ Xf, const float* __restrict__ Xb, int revb,
    const float* __restrict__ Wf, const float* __restrict__ Wb,
    const float* __restrict__ bihf, const float* __restrict__ bhhf,
    const float* __restrict__ bihb, const float* __restrict__ bhhb,
    float* __restrict__ Pf, float* __restrict__ Pb, int K)
{
  const int dirb = blockIdx.z;
  const float* X  = dirb ? Xb : Xf;
  const float* W  = dirb ? Wb : Wf;
  const float* bih = dirb ? bihb : bihf;
  const float* bhh = dirb ? bhhb : bhhf;
  float* Pp = dirb ? Pb : Pf;
  const int rev = dirb ? revb : 0;

  const int bn = blockIdx.x;   // N tile (16)
  const int bm = blockIdx.y;   // M tile (64)
  const int tid = threadIdx.x;
  const int tx = tid & 15, ty = tid >> 4;

  __shared__ float Xs[16][68];   // [k][row], padded
  __shared__ float Ws[16][68];   // [k][col], padded

  float acc[4][4] = {{0.f}};

  const int lrow = tid >> 2;        // 0..63
  const int lk4  = (tid & 3) * 4;   // 0,4,8,12
  const int xrow = bm * 64 + lrow;
  const int xsrc = rev ? (4095 - xrow) : xrow;
  const float* xptr = X + (long)xsrc * K + lk4;
  const float* wptr = W + (long)(bn * 64 + lrow) * K + lk4;

  for (int k0 = 0; k0 < K; k0 += 16) {
    float4 xv = *(const float4*)(xptr + k0);
    float4 wv = *(const float4*)(wptr + k0);
    __syncthreads();   // protect previous iteration's LDS reads
    Xs[lk4 + 0][lrow] = xv.x; Xs[lk4 + 1][lrow] = xv.y;
    Xs[lk4 + 2][lrow] = xv.z; Xs[lk4 + 3][lrow] = xv.w;
    Ws[lk4 + 0][lrow] = wv.x; Ws[lk4 + 1][lrow] = wv.y;
    Ws[lk4 + 2][lrow] = wv.z; Ws[lk4 + 3][lrow] = wv.w;
    __syncthreads();
    #pragma unroll
    for (int kk = 0; kk < 16; ++kk) {
      float4 a = *(const float4*)(&Xs[kk][ty * 4]);
      float4 b = *(const float4*)(&Ws[kk][tx * 4]);
      acc[0][0] = fmaf(a.x, b.x, acc[0][0]); acc[0][1] = fmaf(a.x, b.y, acc[0][1]);
      acc[0][2] = fmaf(a.x, b.z, acc[0][2]); acc[0][3] = fmaf(a.x, b.w, acc[0][3]);
      acc[1][0] = fmaf(a.y, b.x, acc[1][0]); acc[1][1] = fmaf(a.y, b.y, acc[1][1]);
      acc[1][2] = fmaf(a.y, b.z, acc[1][2]); acc[1][3] = fmaf(a.y, b.w, acc[1][3]);
      acc[2][0] = fmaf(a.z, b.x, acc[2][0]); acc[2][1] = fmaf(a.z, b.y, acc[2][1]);
      acc[2][2] = fmaf(a.z, b.z, acc[2][2]); acc[2][3] = fmaf(a.z, b.w, acc[2][3]);
      acc[3][0] = fmaf(a.w, b.x, acc[3][0]); acc[3][1] = fmaf(a.w, b.y, acc[3][1]);
      acc[3][2] = fmaf(a.w, b.z, acc[3][2]); acc[3][3] = fmaf(a.w, b.w, acc[3][3]);
    }
  }

  const int c0 = bn * 64 + tx * 4;
  #pragma unroll
  for (int i = 0; i < 4; ++i) {
    const int r = bm * 64 + ty * 4 + i;
    float4 o4;
    o4.x = acc[i][0] + bih[c0 + 0] + bhh[c0 + 0];
    o4.y = acc[i][1] + bih[c0 + 1] + bhh[c0 + 1];
    o4.z = acc[i][2] + bih[c0 + 2] + bhh[c0 + 2];
    o4.w = acc[i][3] + bih[c0 + 3] + bhh[c0 + 3];
    *(float4*)(&Pp[(long)r * 1024 + c0]) = o4;
  }
}

// Persistent-weight LSTM recurrence. Grid: (4 WGs, 2 dirs), 512 thr/WG.
// Barrier-free: h exchanged via step-tagged 64-bit atomic words.
//   hglob[dir][slot][i] = ((step+1) << 32) | float_bits(h_i^step), slot = step&1.
// Consumers poll tag == step (one element per thread, fully parallel, no RMW,
// no fence: value rides in the same atomic word as the tag). 2 slots make
// producer run-ahead (max 1 step, enforced by the poll) safe.
__global__ __launch_bounds__(512, 2) void lstm_rec(
    const float* __restrict__ Pf, const float* __restrict__ Pb,
    const float* __restrict__ Wf, const float* __restrict__ Wb,
    float* __restrict__ houtf, int strf,
    float* __restrict__ houtb, int strb,
    float* __restrict__ out, int layer,
    unsigned long long* __restrict__ hglob)   // [2 dirs][2 slots][256]
{
  const int w = blockIdx.x;     // 0..3
  const int d = blockIdx.y;     // 0..1
  const int t = threadIdx.x;    // 0..511
  const float* __restrict__ P = d ? Pb : Pf;
  const float* __restrict__ W = d ? Wb : Wf;
  float* hout = d ? houtb : houtf;
  const int hstr = d ? strb : strf;
  unsigned long long* myg = hglob + d * 512;  // 2 slots x 256

  const int kb = t >> 6;   // k-slice 0..7
  const int jg = t & 63;   // output group -> 4 outputs m = jg*4..+3

  // Whh fragment: rows j for m = jg*4+jj (j = (m>>6)*256 + w*64 + (m&63)),
  // k in [kb*32, kb*32+32). 128 floats in registers.
  float wreg[128];
  #pragma unroll
  for (int jj = 0; jj < 4; ++jj) {
    const int m = jg * 4 + jj;
    const int j = (m >> 6) * 256 + w * 64 + (m & 63);
    const float4* wrow = (const float4*)(W + j * 256 + kb * 32);
    #pragma unroll
    for (int kq = 0; kq < 8; ++kq) {
      float4 v = wrow[kq];
      wreg[jj * 32 + kq * 4 + 0] = v.x;
      wreg[jj * 32 + kq * 4 + 1] = v.y;
      wreg[jj * 32 + kq * 4 + 2] = v.z;
      wreg[jj * 32 + kq * 4 + 3] = v.w;
    }
  }

  __shared__ float lds_h[256];
  __shared__ float lds_c[64];
  __shared__ float part[8 * 264];   // [kb][m], padded
  if (t < 64) lds_c[t] = 0.0f;
  // (lds_h filled by poll phase of step 0 from the zeroed hglob)

  const int cell = w * 64 + t;      // valid for t<64
  const long pbase = (long)(t & 63) + w * 64;  // P column base for gates (t<64)

  for (int step = 0; step < T_SEQ; ++step) {
    // P prefetch for the gate wave (independent of h — issue before polling)
    float p0 = 0.f, p1 = 0.f, p2 = 0.f, p3 = 0.f;
    if (t < 64) {
      const float* prow = P + (long)step * 1024 + pbase;
      p0 = prow[0];       // gate i
      p1 = prow[256];     // gate f
      p2 = prow[512];     // gate g
      p3 = prow[768];     // gate o
    }

    // Poll h^(step-1): slot (step+1)&1, tag == step. Element t per thread.
    if (t < 256) {
      const unsigned long long* src = myg + ((step + 1) & 1) * 256 + t;
      unsigned long long v;
      do {
        v = __hip_atomic_load(src, __ATOMIC_RELAXED, __HIP_MEMORY_SCOPE_AGENT);
      } while ((unsigned)(v >> 32) != (unsigned)step);
      lds_h[t] = __uint_as_float((unsigned)v);
    }
    __syncthreads();

    // Matvec partials: 4 outputs x 32 k per thread, h broadcast from LDS.
    float a0 = 0.f, a1 = 0.f, a2 = 0.f, a3 = 0.f;
    const float4* h4 = (const float4*)&lds_h[kb * 32];
    #pragma unroll
    for (int kq = 0; kq < 8; ++kq) {
      float4 hv = h4[kq];
      a0 = fmaf(wreg[0 * 32 + kq * 4 + 0], hv.x, a0);
      a0 = fmaf(wreg[0 * 32 + kq * 4 + 1], hv.y, a0);
      a0 = fmaf(wreg[0 * 32 + kq * 4 + 2], hv.z, a0);
      a0 = fmaf(wreg[0 * 32 + kq * 4 + 3], hv.w, a0);
      a1 = fmaf(wreg[1 * 32 + kq * 4 + 0], hv.x, a1);
      a1 = fmaf(wreg[1 * 32 + kq * 4 + 1], hv.y, a1);
      a1 = fmaf(wreg[1 * 32 + kq * 4 + 2], hv.z, a1);
      a1 = fmaf(wreg[1 * 32 + kq * 4 + 3], hv.w, a1);
      a2 = fmaf(wreg[2 * 32 + kq * 4 + 0], hv.x, a2);
      a2 = fmaf(wreg[2 * 32 + kq * 4 + 1], hv.y, a2);
      a2 = fmaf(wreg[2 * 32 + kq * 4 + 2], hv.z, a2);
      a2 = fmaf(wreg[2 * 32 + kq * 4 + 3], hv.w, a2);
      a3 = fmaf(wreg[3 * 32 + kq * 4 + 0], hv.x, a3);
      a3 = fmaf(wreg[3 * 32 + kq * 4 + 1], hv.y, a3);
      a3 = fmaf(wreg[3 * 32 + kq * 4 + 2], hv.z, a3);
      a3 = fmaf(wreg[3 * 32 + kq * 4 + 3], hv.w, a3);
    }
    float4 av; av.x = a0; av.y = a1; av.z = a2; av.w = a3;
    *(float4*)(&part[kb * 264 + jg * 4]) = av;
    __syncthreads();

    // Gate wave: reduce 8 partials per gate, nonlinearity, publish h.
    if (t < 64) {
      float s0 = p0, s1 = p1, s2 = p2, s3 = p3;
      #pragma unroll
      for (int q = 0; q < 8; ++q) {
        s0 += part[q * 264 + t];          // gate i
        s1 += part[q * 264 + 64 + t];     // gate f
        s2 += part[q * 264 + 128 + t];    // gate g
        s3 += part[q * 264 + 192 + t];    // gate o
      }
      float c = sigmoidf_(s1) * lds_c[t] + sigmoidf_(s0) * tanhf(s2);
      float h = sigmoidf_(s3) * tanhf(c);
      lds_c[t] = c;
      // Publish FIRST (other WGs are waiting on this), then local stores.
      unsigned long long pk =
          ((unsigned long long)(unsigned)(step + 1) << 32) |
          (unsigned long long)__float_as_uint(h);
      __hip_atomic_store(&myg[(step & 1) * 256 + cell], pk,
                         __ATOMIC_RELAXED, __HIP_MEMORY_SCOPE_AGENT);
      hout[(long)step * hstr + cell] = h;
      if (step == T_SEQ - 1) {
        out[layer * 512 + d * 256 + cell] = c;          // cell_memories
        out[1024 + layer * 512 + d * 256 + cell] = h;   // hidden_states
      }
    }
    // No trailing barrier: next iteration's poll-phase __syncthreads plus the
    // tag protocol order everything. part[] reads (gate wave, pre-sync_A of
    // next step) complete before any thread's next part[] write (post-sync_A).
  }
}

extern "C" void kernel_launch(void* const* d_in, const int* in_sizes, int n_in,
                              void* d_out, int out_size, void* d_ws, size_t ws_size,
                              hipStream_t stream) {
  const int*   tokens = (const int*)d_in[0];
  const float* emb    = (const float*)d_in[1];
  const float* fWih0 = (const float*)d_in[2];
  const float* fWhh0 = (const float*)d_in[3];
  const float* fbih0 = (const float*)d_in[4];
  const float* fbhh0 = (const float*)d_in[5];
  const float* fWih1 = (const float*)d_in[6];
  const float* fWhh1 = (const float*)d_in[7];
  const float* fbih1 = (const float*)d_in[8];
  const float* fbhh1 = (const float*)d_in[9];
  const float* bWih0 = (const float*)d_in[10];
  const float* bWhh0 = (const float*)d_in[11];
  const float* bbih0 = (const float*)d_in[12];
  const float* bbhh0 = (const float*)d_in[13];
  const float* bWih1 = (const float*)d_in[14];
  const float* bWhh1 = (const float*)d_in[15];
  const float* bbih1 = (const float*)d_in[16];
  const float* bbhh1 = (const float*)d_in[17];

  float* out = (float*)d_out;
  float* ws  = (float*)d_ws;

  // Workspace layout (float offsets):
  //   [0, 2097152)        X (4096x512); reused as H0f/H0b after gemm0
  //   [2097152, 6291456)  Pf (4096x1024)
  //   [6291456,10485760)  Pb (4096x1024)
  //   [10485760, ...)     hglobA (1024 u64 = 2048 floats), hglobB (1024 u64)
  float* X    = ws;
  float* H0f  = ws;
  float* H0b  = ws + 1048576;
  float* Pf   = ws + 2097152;
  float* Pb   = ws + 6291456;
  unsigned long long* hglobA = (unsigned long long*)(ws + 10485760);
  unsigned long long* hglobB = hglobA + 1024;

  // Zero both exchange buffers: tag 0 == "h^(-1) = 0" initial state.
  hipMemsetAsync(hglobA, 0, 2048 * sizeof(unsigned long long), stream);

  gather_emb<<<2048, 256, 0, stream>>>(tokens, (const float4*)emb, (float4*)X);

  // Layer 0 input projections (K=512); b-direction reads X time-reversed.
  gemm_proj<<<dim3(16, 64, 2), 256, 0, stream>>>(
      X, X, 1, fWih0, bWih0, fbih0, fbhh0, bbih0, bbhh0, Pf, Pb, 512);

  // Layer 0 recurrence: hidden sequences into H0f/H0b (step order), finals to out.
  lstm_rec<<<dim3(4, 2), 512, 0, stream>>>(
      Pf, Pb, fWhh0, bWhh0, H0f, 256, H0b, 256, out, 0, hglobA);

  // Layer 1 input projections (K=256) on layer-0 hidden sequences (no reversal).
  gemm_proj<<<dim3(16, 64, 2), 256, 0, stream>>>(
      H0f, H0b, 0, fWih1, bWih1, fbih1, fbhh1, bbih1, bbhh1, Pf, Pb, 256);

  // Layer 1 recurrence: f -> out rows forward, b -> out rows reversed (+256 col).
  lstm_rec<<<dim3(4, 2), 512, 0, stream>>>(
      Pf, Pb, fWhh1, bWhh1,
      out + 2048, 512,
      out + 2048 + (long)4095 * 512 + 256, -512,
      out, 1, hglobB);
}

// Round 3
// 7481.718 us; speedup vs baseline: 3.7960x; 1.8932x over previous
//
#include <hip/hip_runtime.h>
#include <math.h>

#define T_SEQ 4096

__device__ __forceinline__ float sigmoidf_(float x) {
  return 1.0f / (1.0f + expf(-x));
}

__device__ __forceinline__ unsigned long long pack_h(int tag, float h) {
  return ((unsigned long long)(unsigned)tag << 32) |
         (unsigned long long)__float_as_uint(h);
}

// X[t][k] = emb[tokens[t]][k], as float4
__global__ void gather_emb(const int* __restrict__ tokens,
                           const float4* __restrict__ emb4,
                           float4* __restrict__ X4) {
  int i = blockIdx.x * 256 + threadIdx.x;   // i < 4096*128
  int t = i >> 7;
  int q = i & 127;
  X4[i] = emb4[(long)tokens[t] * 128 + q];
}

// P[t][j] = bias_ih[j] + bias_hh[j] + sum_k X[src(t)][k] * W[j][k]
// M=4096 rows, N=1024 cols. blockIdx.z selects direction (0=f,1=b).
__global__ __launch_bounds__(256) void gemm_proj(
    const float* __restrict__ Xf, const float* __restrict__ Xb, int revb,
    const float* __restrict__ Wf, const float* __restrict__ Wb,
    const float* __restrict__ bihf, const float* __restrict__ bhhf,
    const float* __restrict__ bihb, const float* __restrict__ bhhb,
    float* __restrict__ Pf, float* __restrict__ Pb, int K)
{
  const int dirb = blockIdx.z;
  const float* X  = dirb ? Xb : Xf;
  const float* W  = dirb ? Wb : Wf;
  const float* bih = dirb ? bihb : bihf;
  const float* bhh = dirb ? bhhb : bhhf;
  float* Pp = dirb ? Pb : Pf;
  const int rev = dirb ? revb : 0;

  const int bn = blockIdx.x;   // N tile (16)
  const int bm = blockIdx.y;   // M tile (64)
  const int tid = threadIdx.x;
  const int tx = tid & 15, ty = tid >> 4;

  __shared__ float Xs[16][68];   // [k][row], padded
  __shared__ float Ws[16][68];   // [k][col], padded

  float acc[4][4] = {{0.f}};

  const int lrow = tid >> 2;        // 0..63
  const int lk4  = (tid & 3) * 4;   // 0,4,8,12
  const int xrow = bm * 64 + lrow;
  const int xsrc = rev ? (4095 - xrow) : xrow;
  const float* xptr = X + (long)xsrc * K + lk4;
  const float* wptr = W + (long)(bn * 64 + lrow) * K + lk4;

  for (int k0 = 0; k0 < K; k0 += 16) {
    float4 xv = *(const float4*)(xptr + k0);
    float4 wv = *(const float4*)(wptr + k0);
    __syncthreads();   // protect previous iteration's LDS reads
    Xs[lk4 + 0][lrow] = xv.x; Xs[lk4 + 1][lrow] = xv.y;
    Xs[lk4 + 2][lrow] = xv.z; Xs[lk4 + 3][lrow] = xv.w;
    Ws[lk4 + 0][lrow] = wv.x; Ws[lk4 + 1][lrow] = wv.y;
    Ws[lk4 + 2][lrow] = wv.z; Ws[lk4 + 3][lrow] = wv.w;
    __syncthreads();
    #pragma unroll
    for (int kk = 0; kk < 16; ++kk) {
      float4 a = *(const float4*)(&Xs[kk][ty * 4]);
      float4 b = *(const float4*)(&Ws[kk][tx * 4]);
      acc[0][0] = fmaf(a.x, b.x, acc[0][0]); acc[0][1] = fmaf(a.x, b.y, acc[0][1]);
      acc[0][2] = fmaf(a.x, b.z, acc[0][2]); acc[0][3] = fmaf(a.x, b.w, acc[0][3]);
      acc[1][0] = fmaf(a.y, b.x, acc[1][0]); acc[1][1] = fmaf(a.y, b.y, acc[1][1]);
      acc[1][2] = fmaf(a.y, b.z, acc[1][2]); acc[1][3] = fmaf(a.y, b.w, acc[1][3]);
      acc[2][0] = fmaf(a.z, b.x, acc[2][0]); acc[2][1] = fmaf(a.z, b.y, acc[2][1]);
      acc[2][2] = fmaf(a.z, b.z, acc[2][2]); acc[2][3] = fmaf(a.z, b.w, acc[2][3]);
      acc[3][0] = fmaf(a.w, b.x, acc[3][0]); acc[3][1] = fmaf(a.w, b.y, acc[3][1]);
      acc[3][2] = fmaf(a.w, b.z, acc[3][2]); acc[3][3] = fmaf(a.w, b.w, acc[3][3]);
    }
  }

  const int c0 = bn * 64 + tx * 4;
  #pragma unroll
  for (int i = 0; i < 4; ++i) {
    const int r = bm * 64 + ty * 4 + i;
    float4 o4;
    o4.x = acc[i][0] + bih[c0 + 0] + bhh[c0 + 0];
    o4.y = acc[i][1] + bih[c0 + 1] + bhh[c0 + 1];
    o4.z = acc[i][2] + bih[c0 + 2] + bhh[c0 + 2];
    o4.w = acc[i][3] + bih[c0 + 3] + bhh[c0 + 3];
    *(float4*)(&Pp[(long)r * 1024 + c0]) = o4;
  }
}

// Fused 2-layer bidirectional LSTM recurrence. 24 WGs x 512 threads.
//   WGs 0..7   : layer 0 (4 per dir). WG owns 64 cells; weights in 128 VGPRs.
//   WGs 8..23  : layer 1 (8 per dir). WG owns 32 cells; K=512 contraction
//                (Wih1 over h0[s] ++ Whh1 over h1[s-1]); 128 weight VGPRs.
// h0 exchanged via a 4096-entry step-tagged ring (ring[d][s][i] written once:
// tag s+1 | h-bits) -> extra consumers (L1) can never be clobbered, no flow
// control needed. h1 uses the round-2 2-slot tagged scheme (producers ==
// consumers -> bounded run-ahead, safe). No barriers, no RMW atomics.
__global__ __launch_bounds__(512, 2) void lstm_fused(
    const float* __restrict__ P0f, const float* __restrict__ P0b,
    const float* __restrict__ Whh0f, const float* __restrict__ Whh0b,
    const float* __restrict__ Wih1f, const float* __restrict__ Whh1f,
    const float* __restrict__ bih1f, const float* __restrict__ bhh1f,
    const float* __restrict__ Wih1b, const float* __restrict__ Whh1b,
    const float* __restrict__ bih1b, const float* __restrict__ bhh1b,
    float* __restrict__ out,
    unsigned long long* __restrict__ ring0,   // [2 dirs][4096][256]
    unsigned long long* __restrict__ h1x)     // [2 dirs][2 slots][256]
{
  const int bx = blockIdx.x;
  const int t  = threadIdx.x;

  __shared__ float hx[512];        // L0: h[256] in [0,256); L1: h0[s] ++ h1[s-1]
  __shared__ float lds_c[64];
  __shared__ float part[8 * 264];  // padded partials

  if (t < 64) lds_c[t] = 0.0f;

  if (bx < 8) {
    // ======================= Layer 0 =======================
    const int d = bx >> 2, w = bx & 3;
    const float* __restrict__ P = d ? P0b : P0f;
    const float* __restrict__ W = d ? Whh0b : Whh0f;
    unsigned long long* ring = ring0 + (long)d * T_SEQ * 256;

    const int kb = t >> 6;   // k-slice 0..7 (32 k each)
    const int jg = t & 63;   // -> 4 outputs m = jg*4..+3

    float wreg[128];
    #pragma unroll
    for (int jj = 0; jj < 4; ++jj) {
      const int m = jg * 4 + jj;
      const int j = (m >> 6) * 256 + w * 64 + (m & 63);
      const float4* wrow = (const float4*)(W + (long)j * 256 + kb * 32);
      #pragma unroll
      for (int kq = 0; kq < 8; ++kq) {
        float4 v = wrow[kq];
        wreg[jj * 32 + kq * 4 + 0] = v.x;
        wreg[jj * 32 + kq * 4 + 1] = v.y;
        wreg[jj * 32 + kq * 4 + 2] = v.z;
        wreg[jj * 32 + kq * 4 + 3] = v.w;
      }
    }

    const int cell = w * 64 + (t & 63);          // for t<64
    const long pbase = (long)(t & 63) + w * 64;  // P column base (t<64)

    for (int s = 0; s < T_SEQ; ++s) {
      float p0 = 0.f, p1 = 0.f, p2 = 0.f, p3 = 0.f;
      if (t < 64) {
        const float* prow = P + (long)s * 1024 + pbase;
        p0 = prow[0]; p1 = prow[256]; p2 = prow[512]; p3 = prow[768];
      }

      if (s == 0) {
        if (t < 256) hx[t] = 0.0f;
      } else if (t < 256) {
        const unsigned long long* src = ring + (long)(s - 1) * 256 + t;
        unsigned long long v;
        do {
          v = __hip_atomic_load(src, __ATOMIC_RELAXED, __HIP_MEMORY_SCOPE_AGENT);
        } while ((unsigned)(v >> 32) != (unsigned)s);
        hx[t] = __uint_as_float((unsigned)v);
      }
      __syncthreads();

      float a0 = 0.f, a1 = 0.f, a2 = 0.f, a3 = 0.f;
      const float4* h4 = (const float4*)&hx[kb * 32];
      #pragma unroll
      for (int kq = 0; kq < 8; ++kq) {
        float4 hv = h4[kq];
        a0 = fmaf(wreg[0 * 32 + kq * 4 + 0], hv.x, a0);
        a0 = fmaf(wreg[0 * 32 + kq * 4 + 1], hv.y, a0);
        a0 = fmaf(wreg[0 * 32 + kq * 4 + 2], hv.z, a0);
        a0 = fmaf(wreg[0 * 32 + kq * 4 + 3], hv.w, a0);
        a1 = fmaf(wreg[1 * 32 + kq * 4 + 0], hv.x, a1);
        a1 = fmaf(wreg[1 * 32 + kq * 4 + 1], hv.y, a1);
        a1 = fmaf(wreg[1 * 32 + kq * 4 + 2], hv.z, a1);
        a1 = fmaf(wreg[1 * 32 + kq * 4 + 3], hv.w, a1);
        a2 = fmaf(wreg[2 * 32 + kq * 4 + 0], hv.x, a2);
        a2 = fmaf(wreg[2 * 32 + kq * 4 + 1], hv.y, a2);
        a2 = fmaf(wreg[2 * 32 + kq * 4 + 2], hv.z, a2);
        a2 = fmaf(wreg[2 * 32 + kq * 4 + 3], hv.w, a2);
        a3 = fmaf(wreg[3 * 32 + kq * 4 + 0], hv.x, a3);
        a3 = fmaf(wreg[3 * 32 + kq * 4 + 1], hv.y, a3);
        a3 = fmaf(wreg[3 * 32 + kq * 4 + 2], hv.z, a3);
        a3 = fmaf(wreg[3 * 32 + kq * 4 + 3], hv.w, a3);
      }
      float4 av; av.x = a0; av.y = a1; av.z = a2; av.w = a3;
      *(float4*)(&part[kb * 264 + jg * 4]) = av;
      __syncthreads();

      if (t < 64) {
        float s0 = p0, s1 = p1, s2 = p2, s3 = p3;
        #pragma unroll
        for (int q = 0; q < 8; ++q) {
          s0 += part[q * 264 + t];
          s1 += part[q * 264 + 64 + t];
          s2 += part[q * 264 + 128 + t];
          s3 += part[q * 264 + 192 + t];
        }
        float c = sigmoidf_(s1) * lds_c[t] + sigmoidf_(s0) * tanhf(s2);
        float h = sigmoidf_(s3) * tanhf(c);
        lds_c[t] = c;
        __hip_atomic_store(ring + (long)s * 256 + cell, pack_h(s + 1, h),
                           __ATOMIC_RELAXED, __HIP_MEMORY_SCOPE_AGENT);
        if (s == T_SEQ - 1) {
          out[d * 256 + cell] = c;           // cell_memories layer 0
          out[1024 + d * 256 + cell] = h;    // hidden_states layer 0
        }
      }
      // part[] reuse across steps is safe: gate-wave reads happen before it
      // reaches the next step's first __syncthreads.
    }
  } else {
    // ======================= Layer 1 =======================
    const int i1 = bx - 8, d = i1 >> 3, w1 = i1 & 7;
    const float* __restrict__ Wih = d ? Wih1b : Wih1f;
    const float* __restrict__ Whh = d ? Whh1b : Whh1f;
    const float* __restrict__ bih = d ? bih1b : bih1f;
    const float* __restrict__ bhh = d ? bhh1b : bhh1f;
    unsigned long long* ring = ring0 + (long)d * T_SEQ * 256;
    unsigned long long* slot = h1x + d * 512;
    float* hout = d ? (out + 2048 + (long)4095 * 512 + 256) : (out + 2048);
    const long hstr = d ? -512 : 512;

    const int kb = t >> 6;   // k-slice 0..7 (64 k each of combined K=512)
    const int jg = t & 63;   // -> 2 outputs m = jg*2, jg*2+1 (m in [0,128))

    // Weights: row j(m) = (m>>5)*256 + w1*32 + (m&31); k<256 -> Wih1, else Whh1.
    float wreg[2][64];
    #pragma unroll
    for (int rr = 0; rr < 2; ++rr) {
      const int m = jg * 2 + rr;
      const int j = (m >> 5) * 256 + w1 * 32 + (m & 31);
      const float* srcw = (kb < 4) ? (Wih + (long)j * 256 + kb * 64)
                                   : (Whh + (long)j * 256 + (kb - 4) * 64);
      const float4* s4 = (const float4*)srcw;
      #pragma unroll
      for (int q = 0; q < 16; ++q) {
        float4 v = s4[q];
        wreg[rr][q * 4 + 0] = v.x; wreg[rr][q * 4 + 1] = v.y;
        wreg[rr][q * 4 + 2] = v.z; wreg[rr][q * 4 + 3] = v.w;
      }
    }

    const int cell = w1 * 32 + (t & 31);   // for t<32
    float b0 = 0.f, b1 = 0.f, b2 = 0.f, b3 = 0.f;
    if (t < 32) {
      b0 = bih[cell] + bhh[cell];
      b1 = bih[256 + cell] + bhh[256 + cell];
      b2 = bih[512 + cell] + bhh[512 + cell];
      b3 = bih[768 + cell] + bhh[768 + cell];
    }

    for (int s = 0; s < T_SEQ; ++s) {
      if (t < 256) {
        // x-input: h0[s] from the ring (tag s+1)
        const unsigned long long* src = ring + (long)s * 256 + t;
        unsigned long long v;
        do {
          v = __hip_atomic_load(src, __ATOMIC_RELAXED, __HIP_MEMORY_SCOPE_AGENT);
        } while ((unsigned)(v >> 32) != (unsigned)(s + 1));
        hx[t] = __uint_as_float((unsigned)v);
      } else {
        // recurrent input: h1[s-1], slot (s+1)&1, tag s
        const unsigned long long* src = slot + ((s + 1) & 1) * 256 + (t - 256);
        unsigned long long v;
        do {
          v = __hip_atomic_load(src, __ATOMIC_RELAXED, __HIP_MEMORY_SCOPE_AGENT);
        } while ((unsigned)(v >> 32) != (unsigned)s);
        hx[t] = __uint_as_float((unsigned)v);
      }
      __syncthreads();

      float a0 = 0.f, a1 = 0.f;
      const float4* h4 = (const float4*)&hx[kb * 64];
      #pragma unroll
      for (int q = 0; q < 16; ++q) {
        float4 hv = h4[q];
        a0 = fmaf(wreg[0][q * 4 + 0], hv.x, a0);
        a0 = fmaf(wreg[0][q * 4 + 1], hv.y, a0);
        a0 = fmaf(wreg[0][q * 4 + 2], hv.z, a0);
        a0 = fmaf(wreg[0][q * 4 + 3], hv.w, a0);
        a1 = fmaf(wreg[1][q * 4 + 0], hv.x, a1);
        a1 = fmaf(wreg[1][q * 4 + 1], hv.y, a1);
        a1 = fmaf(wreg[1][q * 4 + 2], hv.z, a1);
        a1 = fmaf(wreg[1][q * 4 + 3], hv.w, a1);
      }
      float2 av2; av2.x = a0; av2.y = a1;
      *(float2*)(&part[kb * 264 + jg * 2]) = av2;
      __syncthreads();

      if (t < 32) {
        float s0 = b0, s1 = b1, s2 = b2, s3 = b3;
        #pragma unroll
        for (int q = 0; q < 8; ++q) {
          s0 += part[q * 264 + t];          // gate i (m = 0..31)
          s1 += part[q * 264 + 32 + t];     // gate f
          s2 += part[q * 264 + 64 + t];     // gate g
          s3 += part[q * 264 + 96 + t];     // gate o
        }
        float c = sigmoidf_(s1) * lds_c[t] + sigmoidf_(s0) * tanhf(s2);
        float h = sigmoidf_(s3) * tanhf(c);
        lds_c[t] = c;
        __hip_atomic_store(&slot[(s & 1) * 256 + cell], pack_h(s + 1, h),
                           __ATOMIC_RELAXED, __HIP_MEMORY_SCOPE_AGENT);
        hout[(long)s * hstr + cell] = h;    // outputs
        if (s == T_SEQ - 1) {
          out[512 + d * 256 + cell] = c;          // cell_memories layer 1
          out[1024 + 512 + d * 256 + cell] = h;   // hidden_states layer 1
        }
      }
    }
  }
}

extern "C" void kernel_launch(void* const* d_in, const int* in_sizes, int n_in,
                              void* d_out, int out_size, void* d_ws, size_t ws_size,
                              hipStream_t stream) {
  const int*   tokens = (const int*)d_in[0];
  const float* emb    = (const float*)d_in[1];
  const float* fWih0 = (const float*)d_in[2];
  const float* fWhh0 = (const float*)d_in[3];
  const float* fbih0 = (const float*)d_in[4];
  const float* fbhh0 = (const float*)d_in[5];
  const float* fWih1 = (const float*)d_in[6];
  const float* fWhh1 = (const float*)d_in[7];
  const float* fbih1 = (const float*)d_in[8];
  const float* fbhh1 = (const float*)d_in[9];
  const float* bWih0 = (const float*)d_in[10];
  const float* bWhh0 = (const float*)d_in[11];
  const float* bbih0 = (const float*)d_in[12];
  const float* bbhh0 = (const float*)d_in[13];
  const float* bWih1 = (const float*)d_in[14];
  const float* bWhh1 = (const float*)d_in[15];
  const float* bbih1 = (const float*)d_in[16];
  const float* bbhh1 = (const float*)d_in[17];

  float* out = (float*)d_out;
  float* ws  = (float*)d_ws;

  // Workspace layout (float offsets):
  //   [0, 4194304)          h0 rings: [2 dirs][4096][256] u64 (16 MB).
  //                         X (4096x512, 8 MB) overlaps [0, 2097152) — dead
  //                         after gemm_proj; rings memset afterwards.
  //   [4194304,  8388608)   P0f (4096x1024)
  //   [8388608, 12582912)   P0b (4096x1024)
  //   [12582912, 12584960)  h1x: [2 dirs][2 slots][256] u64 (8 KB)
  float* X   = ws;
  float* P0f = ws + 4194304;
  float* P0b = ws + 8388608;
  unsigned long long* ring0 = (unsigned long long*)ws;
  unsigned long long* h1x   = (unsigned long long*)(ws + 12582912);

  gather_emb<<<2048, 256, 0, stream>>>(tokens, (const float4*)emb, (float4*)X);

  // Layer 0 input projections (K=512); b-direction reads X time-reversed.
  gemm_proj<<<dim3(16, 64, 2), 256, 0, stream>>>(
      X, X, 1, fWih0, bWih0, fbih0, fbhh0, bbih0, bbhh0, P0f, P0b, 512);

  // Reset exchange buffers (tag 0 = "not ready" for rings, "h[-1]=0" for h1x).
  // Stream-ordered after gemm_proj (which consumed the overlapping X region).
  hipMemsetAsync(ring0, 0, (size_t)2 * T_SEQ * 256 * sizeof(unsigned long long), stream);
  hipMemsetAsync(h1x, 0, 1024 * sizeof(unsigned long long), stream);

  // Fused 2-layer bidirectional recurrence: 8 L0 WGs + 16 L1 WGs.
  lstm_fused<<<dim3(24), 512, 0, stream>>>(
      P0f, P0b, fWhh0, bWhh0,
      fWih1, fWhh1, fbih1, fbhh1,
      bWih1, bWhh1, bbih1, bbhh1,
      out, ring0, h1x);
}

// Round 5
// 7025.958 us; speedup vs baseline: 4.0423x; 1.0649x over previous
//
#include <hip/hip_runtime.h>
#include <math.h>

#define T_SEQ 4096
#define NWG_LAUNCH 512   // oversubscribed so rescue-claiming always completes

__device__ __forceinline__ float sigmoidf_(float x) {
  return 1.0f / (1.0f + expf(-x));
}

__device__ __forceinline__ unsigned long long pack_h(int tag, float h) {
  return ((unsigned long long)(unsigned)tag << 32) |
         (unsigned long long)__float_as_uint(h);
}

// L1-bypassing load, served by the local XCD's L2 (fast path).
__device__ __forceinline__ unsigned long long ld_sc0(const unsigned long long* p) {
  unsigned long long v;
  asm volatile("global_load_dwordx2 %0, %1, off sc0\n\ts_waitcnt vmcnt(0)"
               : "=v"(v) : "v"(p) : "memory");
  return v;
}
// L1+L2-bypassing load, served at the device coherence point (truth path).
__device__ __forceinline__ unsigned long long ld_mall(const unsigned long long* p) {
  unsigned long long v;
  asm volatile("global_load_dwordx2 %0, %1, off sc0 sc1\n\ts_waitcnt vmcnt(0)"
               : "=v"(v) : "v"(p) : "memory");
  return v;
}
// Publish: local-L2 write-through copy + MALL-visible copy. Same 8B value to
// the same address -> order-independent; consumers can use either path.
__device__ __forceinline__ void st_pub(unsigned long long* p, unsigned long long v) {
  asm volatile("global_store_dwordx2 %0, %1, off sc0\n\t"
               "global_store_dwordx2 %0, %1, off sc0 sc1"
               :: "v"(p), "v"(v) : "memory");
}
// Hang-proof poll: mostly-fast sc0 probes, every 4th probe reads MALL truth.
__device__ __forceinline__ float poll_h(const unsigned long long* p, unsigned want) {
  int it = 0;
  for (;;) {
    unsigned long long v = ((it & 3) == 3) ? ld_mall(p) : ld_sc0(p);
    if ((unsigned)(v >> 32) == want) return __uint_as_float((unsigned)v);
    ++it;
  }
}

// X[t][k] = emb[tokens[t]][k], as float4
__global__ void gather_emb(const int* __restrict__ tokens,
                           const float4* __restrict__ emb4,
                           float4* __restrict__ X4) {
  int i = blockIdx.x * 256 + threadIdx.x;   // i < 4096*128
  int t = i >> 7;
  int q = i & 127;
  X4[i] = emb4[(long)tokens[t] * 128 + q];
}

// P[t][j] = bias_ih[j] + bias_hh[j] + sum_k X[src(t)][k] * W[j][k]
__global__ __launch_bounds__(256) void gemm_proj(
    const float* __restrict__ Xf, const float* __restrict__ Xb, int revb,
    const float* __restrict__ Wf, const float* __restrict__ Wb,
    const float* __restrict__ bihf, const float* __restrict__ bhhf,
    const float* __restrict__ bihb, const float* __restrict__ bhhb,
    float* __restrict__ Pf, float* __restrict__ Pb, int K)
{
  const int dirb = blockIdx.z;
  const float* X  = dirb ? Xb : Xf;
  const float* W  = dirb ? Wb : Wf;
  const float* bih = dirb ? bihb : bihf;
  const float* bhh = dirb ? bhhb : bhhf;
  float* Pp = dirb ? Pb : Pf;
  const int rev = dirb ? revb : 0;

  const int bn = blockIdx.x;   // N tile (16)
  const int bm = blockIdx.y;   // M tile (64)
  const int tid = threadIdx.x;
  const int tx = tid & 15, ty = tid >> 4;

  __shared__ float Xs[16][68];
  __shared__ float Ws[16][68];

  float acc[4][4] = {{0.f}};

  const int lrow = tid >> 2;
  const int lk4  = (tid & 3) * 4;
  const int xrow = bm * 64 + lrow;
  const int xsrc = rev ? (4095 - xrow) : xrow;
  const float* xptr = X + (long)xsrc * K + lk4;
  const float* wptr = W + (long)(bn * 64 + lrow) * K + lk4;

  for (int k0 = 0; k0 < K; k0 += 16) {
    float4 xv = *(const float4*)(xptr + k0);
    float4 wv = *(const float4*)(wptr + k0);
    __syncthreads();
    Xs[lk4 + 0][lrow] = xv.x; Xs[lk4 + 1][lrow] = xv.y;
    Xs[lk4 + 2][lrow] = xv.z; Xs[lk4 + 3][lrow] = xv.w;
    Ws[lk4 + 0][lrow] = wv.x; Ws[lk4 + 1][lrow] = wv.y;
    Ws[lk4 + 2][lrow] = wv.z; Ws[lk4 + 3][lrow] = wv.w;
    __syncthreads();
    #pragma unroll
    for (int kk = 0; kk < 16; ++kk) {
      float4 a = *(const float4*)(&Xs[kk][ty * 4]);
      float4 b = *(const float4*)(&Ws[kk][tx * 4]);
      acc[0][0] = fmaf(a.x, b.x, acc[0][0]); acc[0][1] = fmaf(a.x, b.y, acc[0][1]);
      acc[0][2] = fmaf(a.x, b.z, acc[0][2]); acc[0][3] = fmaf(a.x, b.w, acc[0][3]);
      acc[1][0] = fmaf(a.y, b.x, acc[1][0]); acc[1][1] = fmaf(a.y, b.y, acc[1][1]);
      acc[1][2] = fmaf(a.y, b.z, acc[1][2]); acc[1][3] = fmaf(a.y, b.w, acc[1][3]);
      acc[2][0] = fmaf(a.z, b.x, acc[2][0]); acc[2][1] = fmaf(a.z, b.y, acc[2][1]);
      acc[2][2] = fmaf(a.z, b.z, acc[2][2]); acc[2][3] = fmaf(a.z, b.w, acc[2][3]);
      acc[3][0] = fmaf(a.w, b.x, acc[3][0]); acc[3][1] = fmaf(a.w, b.y, acc[3][1]);
      acc[3][2] = fmaf(a.w, b.z, acc[3][2]); acc[3][3] = fmaf(a.w, b.w, acc[3][3]);
    }
  }

  const int c0 = bn * 64 + tx * 4;
  #pragma unroll
  for (int i = 0; i < 4; ++i) {
    const int r = bm * 64 + ty * 4 + i;
    float4 o4;
    o4.x = acc[i][0] + bih[c0 + 0] + bhh[c0 + 0];
    o4.y = acc[i][1] + bih[c0 + 1] + bhh[c0 + 1];
    o4.z = acc[i][2] + bih[c0 + 2] + bhh[c0 + 2];
    o4.w = acc[i][3] + bih[c0 + 3] + bhh[c0 + 3];
    *(float4*)(&Pp[(long)r * 1024 + c0]) = o4;
  }
}

// Fused 2-layer bidirectional LSTM recurrence with best-effort XCD colocation.
// Roles: 0-11 forward (0-3 L0f, 4-11 L1f), 12-23 backward. Preferred pools:
// XCD0 -> forward, XCD1 -> backward; rescue pass guarantees every role is
// claimed regardless of dispatch placement or a misbehaving XCC_ID read.
// Exchange protocol identical to round 3 (tagged 8B words); publish reaches
// both local L2 and MALL, poll interleaves L2-fast and MALL-truth loads ->
// correct and hang-free under every coherence behavior, fast when colocated.
__global__ __launch_bounds__(512, 2) void lstm_fused(
    const float* __restrict__ P0f, const float* __restrict__ P0b,
    const float* __restrict__ Whh0f, const float* __restrict__ Whh0b,
    const float* __restrict__ Wih1f, const float* __restrict__ Whh1f,
    const float* __restrict__ bih1f, const float* __restrict__ bhh1f,
    const float* __restrict__ Wih1b, const float* __restrict__ Whh1b,
    const float* __restrict__ bih1b, const float* __restrict__ bhh1b,
    float* __restrict__ out,
    unsigned long long* __restrict__ ring0,   // [2 dirs][4096][256]
    unsigned long long* __restrict__ h1x,     // [2 dirs][2 slots][256]
    int* __restrict__ flags)                  // [24] role flags + [24] check-in
{
  const int t = threadIdx.x;

  __shared__ int role_s;
  if (t == 0) {
    int xcd;
    // HW_REG_XCC_ID = hwreg id 20 (numeric encoding; no symbolic-name dep).
    asm volatile("s_getreg_b32 %0, hwreg(20, 0, 32)" : "=s"(xcd));
    xcd &= 7;
    int role = -1;
    const int lo = (xcd == 0) ? 0 : (xcd == 1 ? 12 : -1);
    if (lo >= 0) {
      for (int r = lo; r < lo + 12 && role < 0; ++r)
        if (atomicCAS(&flags[r], 0, 1) == 0) role = r;
    }
    const int n = atomicAdd(&flags[24], 1) + 1;   // check-in AFTER claim try
    if (role < 0 && n > NWG_LAUNCH - 32) {
      // Rescue: all earlier WGs have finished claiming; grab any free role.
      for (int r = 0; r < 24 && role < 0; ++r)
        if (atomicCAS(&flags[r], 0, 1) == 0) role = r;
    }
    role_s = role;
  }
  __syncthreads();
  const int role = role_s;
  if (role < 0) return;

  const int d   = role < 12 ? 0 : 1;   // 0 = forward, 1 = backward
  const int sub = role < 12 ? role : role - 12;   // 0-3: L0, 4-11: L1

  __shared__ float hx[512];        // L0: h[256]; L1: h0[s] ++ h1[s-1]
  __shared__ float lds_c[64];
  __shared__ float part[8 * 264];

  if (t < 64) lds_c[t] = 0.0f;

  unsigned long long* ring = ring0 + (long)d * T_SEQ * 256;

  if (sub < 4) {
    // ======================= Layer 0 =======================
    const int w = sub;
    const float* __restrict__ P = d ? P0b : P0f;
    const float* __restrict__ W = d ? Whh0b : Whh0f;

    const int kb = t >> 6;   // k-slice 0..7 (32 k each)
    const int jg = t & 63;   // -> 4 outputs m = jg*4..+3

    float wreg[128];
    #pragma unroll
    for (int jj = 0; jj < 4; ++jj) {
      const int m = jg * 4 + jj;
      const int j = (m >> 6) * 256 + w * 64 + (m & 63);
      const float4* wrow = (const float4*)(W + (long)j * 256 + kb * 32);
      #pragma unroll
      for (int kq = 0; kq < 8; ++kq) {
        float4 v = wrow[kq];
        wreg[jj * 32 + kq * 4 + 0] = v.x;
        wreg[jj * 32 + kq * 4 + 1] = v.y;
        wreg[jj * 32 + kq * 4 + 2] = v.z;
        wreg[jj * 32 + kq * 4 + 3] = v.w;
      }
    }

    const int cell = w * 64 + (t & 63);          // for t<64
    const long pbase = (long)(t & 63) + w * 64;  // P column base (t<64)

    for (int s = 0; s < T_SEQ; ++s) {
      float p0 = 0.f, p1 = 0.f, p2 = 0.f, p3 = 0.f;
      if (t < 64) {
        const float* prow = P + (long)s * 1024 + pbase;
        p0 = prow[0]; p1 = prow[256]; p2 = prow[512]; p3 = prow[768];
      }

      if (s == 0) {
        if (t < 256) hx[t] = 0.0f;
      } else if (t < 256) {
        hx[t] = poll_h(ring + (long)(s - 1) * 256 + t, (unsigned)s);
      }
      __syncthreads();

      float a0 = 0.f, a1 = 0.f, a2 = 0.f, a3 = 0.f;
      const float4* h4 = (const float4*)&hx[kb * 32];
      #pragma unroll
      for (int kq = 0; kq < 8; ++kq) {
        float4 hv = h4[kq];
        a0 = fmaf(wreg[0 * 32 + kq * 4 + 0], hv.x, a0);
        a0 = fmaf(wreg[0 * 32 + kq * 4 + 1], hv.y, a0);
        a0 = fmaf(wreg[0 * 32 + kq * 4 + 2], hv.z, a0);
        a0 = fmaf(wreg[0 * 32 + kq * 4 + 3], hv.w, a0);
        a1 = fmaf(wreg[1 * 32 + kq * 4 + 0], hv.x, a1);
        a1 = fmaf(wreg[1 * 32 + kq * 4 + 1], hv.y, a1);
        a1 = fmaf(wreg[1 * 32 + kq * 4 + 2], hv.z, a1);
        a1 = fmaf(wreg[1 * 32 + kq * 4 + 3], hv.w, a1);
        a2 = fmaf(wreg[2 * 32 + kq * 4 + 0], hv.x, a2);
        a2 = fmaf(wreg[2 * 32 + kq * 4 + 1], hv.y, a2);
        a2 = fmaf(wreg[2 * 32 + kq * 4 + 2], hv.z, a2);
        a2 = fmaf(wreg[2 * 32 + kq * 4 + 3], hv.w, a2);
        a3 = fmaf(wreg[3 * 32 + kq * 4 + 0], hv.x, a3);
        a3 = fmaf(wreg[3 * 32 + kq * 4 + 1], hv.y, a3);
        a3 = fmaf(wreg[3 * 32 + kq * 4 + 2], hv.z, a3);
        a3 = fmaf(wreg[3 * 32 + kq * 4 + 3], hv.w, a3);
      }
      float4 av; av.x = a0; av.y = a1; av.z = a2; av.w = a3;
      *(float4*)(&part[kb * 264 + jg * 4]) = av;
      __syncthreads();

      if (t < 64) {
        float s0 = p0, s1 = p1, s2 = p2, s3 = p3;
        #pragma unroll
        for (int q = 0; q < 8; ++q) {
          s0 += part[q * 264 + t];
          s1 += part[q * 264 + 64 + t];
          s2 += part[q * 264 + 128 + t];
          s3 += part[q * 264 + 192 + t];
        }
        float c = sigmoidf_(s1) * lds_c[t] + sigmoidf_(s0) * tanhf(s2);
        float h = sigmoidf_(s3) * tanhf(c);
        lds_c[t] = c;
        st_pub(ring + (long)s * 256 + cell, pack_h(s + 1, h));
        if (s == T_SEQ - 1) {
          out[d * 256 + cell] = c;           // cell_memories layer 0
          out[1024 + d * 256 + cell] = h;    // hidden_states layer 0
        }
      }
    }
  } else {
    // ======================= Layer 1 =======================
    const int w1 = sub - 4;   // 0..7
    const float* __restrict__ Wih = d ? Wih1b : Wih1f;
    const float* __restrict__ Whh = d ? Whh1b : Whh1f;
    const float* __restrict__ bih = d ? bih1b : bih1f;
    const float* __restrict__ bhh = d ? bhh1b : bhh1f;
    unsigned long long* slot = h1x + d * 512;
    float* hout = d ? (out + 2048 + (long)4095 * 512 + 256) : (out + 2048);
    const long hstr = d ? -512 : 512;

    const int kb = t >> 6;   // k-slice 0..7 (64 k each of combined K=512)
    const int jg = t & 63;   // -> 2 outputs m = jg*2, jg*2+1

    float wreg[2][64];
    #pragma unroll
    for (int rr = 0; rr < 2; ++rr) {
      const int m = jg * 2 + rr;
      const int j = (m >> 5) * 256 + w1 * 32 + (m & 31);
      const float* srcw = (kb < 4) ? (Wih + (long)j * 256 + kb * 64)
                                   : (Whh + (long)j * 256 + (kb - 4) * 64);
      const float4* s4 = (const float4*)srcw;
      #pragma unroll
      for (int q = 0; q < 16; ++q) {
        float4 v = s4[q];
        wreg[rr][q * 4 + 0] = v.x; wreg[rr][q * 4 + 1] = v.y;
        wreg[rr][q * 4 + 2] = v.z; wreg[rr][q * 4 + 3] = v.w;
      }
    }

    const int cell = w1 * 32 + (t & 31);   // for t<32
    float b0 = 0.f, b1 = 0.f, b2 = 0.f, b3 = 0.f;
    if (t < 32) {
      b0 = bih[cell] + bhh[cell];
      b1 = bih[256 + cell] + bhh[256 + cell];
      b2 = bih[512 + cell] + bhh[512 + cell];
      b3 = bih[768 + cell] + bhh[768 + cell];
    }

    for (int s = 0; s < T_SEQ; ++s) {
      if (t < 256) {
        // x-input: h0[s] from the ring (tag s+1)
        hx[t] = poll_h(ring + (long)s * 256 + t, (unsigned)(s + 1));
      } else {
        // recurrent input: h1[s-1] from slot (s+1)&1 (tag s)
        hx[t] = poll_h(slot + ((s + 1) & 1) * 256 + (t - 256), (unsigned)s);
      }
      __syncthreads();

      float a0 = 0.f, a1 = 0.f;
      const float4* h4 = (const float4*)&hx[kb * 64];
      #pragma unroll
      for (int q = 0; q < 16; ++q) {
        float4 hv = h4[q];
        a0 = fmaf(wreg[0][q * 4 + 0], hv.x, a0);
        a0 = fmaf(wreg[0][q * 4 + 1], hv.y, a0);
        a0 = fmaf(wreg[0][q * 4 + 2], hv.z, a0);
        a0 = fmaf(wreg[0][q * 4 + 3], hv.w, a0);
        a1 = fmaf(wreg[1][q * 4 + 0], hv.x, a1);
        a1 = fmaf(wreg[1][q * 4 + 1], hv.y, a1);
        a1 = fmaf(wreg[1][q * 4 + 2], hv.z, a1);
        a1 = fmaf(wreg[1][q * 4 + 3], hv.w, a1);
      }
      float2 av2; av2.x = a0; av2.y = a1;
      *(float2*)(&part[kb * 264 + jg * 2]) = av2;
      __syncthreads();

      if (t < 32) {
        float s0 = b0, s1 = b1, s2 = b2, s3 = b3;
        #pragma unroll
        for (int q = 0; q < 8; ++q) {
          s0 += part[q * 264 + t];
          s1 += part[q * 264 + 32 + t];
          s2 += part[q * 264 + 64 + t];
          s3 += part[q * 264 + 96 + t];
        }
        float c = sigmoidf_(s1) * lds_c[t] + sigmoidf_(s0) * tanhf(s2);
        float h = sigmoidf_(s3) * tanhf(c);
        lds_c[t] = c;
        st_pub(&slot[(s & 1) * 256 + cell], pack_h(s + 1, h));
        hout[(long)s * hstr + cell] = h;    // outputs
        if (s == T_SEQ - 1) {
          out[512 + d * 256 + cell] = c;          // cell_memories layer 1
          out[1024 + 512 + d * 256 + cell] = h;   // hidden_states layer 1
        }
      }
    }
  }
}

extern "C" void kernel_launch(void* const* d_in, const int* in_sizes, int n_in,
                              void* d_out, int out_size, void* d_ws, size_t ws_size,
                              hipStream_t stream) {
  const int*   tokens = (const int*)d_in[0];
  const float* emb    = (const float*)d_in[1];
  const float* fWih0 = (const float*)d_in[2];
  const float* fWhh0 = (const float*)d_in[3];
  const float* fbih0 = (const float*)d_in[4];
  const float* fbhh0 = (const float*)d_in[5];
  const float* fWih1 = (const float*)d_in[6];
  const float* fWhh1 = (const float*)d_in[7];
  const float* fbih1 = (const float*)d_in[8];
  const float* fbhh1 = (const float*)d_in[9];
  const float* bWih0 = (const float*)d_in[10];
  const float* bWhh0 = (const float*)d_in[11];
  const float* bbih0 = (const float*)d_in[12];
  const float* bbhh0 = (const float*)d_in[13];
  const float* bWih1 = (const float*)d_in[14];
  const float* bWhh1 = (const float*)d_in[15];
  const float* bbih1 = (const float*)d_in[16];
  const float* bbhh1 = (const float*)d_in[17];

  float* out = (float*)d_out;
  float* ws  = (float*)d_ws;

  // Workspace layout (float offsets):
  //   [0, 4194304)          h0 rings: [2 dirs][4096][256] u64 (16 MB).
  //                         X (4096x512, 8 MB) overlaps [0, 2097152) — dead
  //                         after gemm_proj; rings memset afterwards.
  //   [4194304,  8388608)   P0f (4096x1024)
  //   [8388608, 12582912)   P0b (4096x1024)
  //   [12582912, 12584960)  h1x: [2 dirs][2 slots][256] u64 (8 KB)
  //   [12584960, ...)       role flags (24 ints) + check-in counter (1 int)
  float* X   = ws;
  float* P0f = ws + 4194304;
  float* P0b = ws + 8388608;
  unsigned long long* ring0 = (unsigned long long*)ws;
  unsigned long long* h1x   = (unsigned long long*)(ws + 12582912);
  int* flags = (int*)(ws + 12584960);

  gather_emb<<<2048, 256, 0, stream>>>(tokens, (const float4*)emb, (float4*)X);

  // Layer 0 input projections (K=512); b-direction reads X time-reversed.
  gemm_proj<<<dim3(16, 64, 2), 256, 0, stream>>>(
      X, X, 1, fWih0, bWih0, fbih0, fbhh0, bbih0, bbhh0, P0f, P0b, 512);

  // Reset exchange buffers + role state (tag 0 = "not ready" / "h[-1]=0").
  hipMemsetAsync(ring0, 0, (size_t)2 * T_SEQ * 256 * sizeof(unsigned long long), stream);
  hipMemsetAsync(h1x, 0, 1024 * sizeof(unsigned long long) + 32 * sizeof(int), stream);

  // Fused recurrence: 512 WGs; 24 claim roles (preferred: fwd on XCD0,
  // bwd on XCD1; rescue pass guarantees full claim), rest exit.
  lstm_fused<<<dim3(NWG_LAUNCH), 512, 0, stream>>>(
      P0f, P0b, fWhh0, bWhh0,
      fWih1, fWhh1, fbih1, fbhh1,
      bWih1, bWhh1, bbih1, bbhh1,
      out, ring0, h1x, flags);
}